// Round 1
// baseline (361.028 us; speedup 1.0000x reference)
//
#include <hip/hip_runtime.h>
#include <math.h>

#define EPSBN 1e-5f

constexpr int CIN  = 128;
constexpr int MID  = 64;
constexpr int COUT = 256;
constexpr int KNB  = 32;
constexpr int PKP  = 15;

__device__ __forceinline__ float lrelu(float x) { return x >= 0.0f ? x : 0.1f * x; }

// ---------------------------------------------------------------------------
// K1: fused pointwise conv1 (features@W1 -> bn1 -> lrelu -> xbuf[N,64])
//     and shortcut      (features@Ws -> bns -> lrelu -> scbuf[N,256])
// grid (N/64, 5): by==0 -> x path (64 cols), by 1..4 -> shortcut col-slices.
// 64x64 output tile, 256 threads, 4x4 per thread, K=128 staged once in LDS.
// ---------------------------------------------------------------------------
__global__ __launch_bounds__(256) void k1_pointwise(
    const float* __restrict__ F,
    const float* __restrict__ W1, const float* __restrict__ Ws,
    const float* __restrict__ g1, const float* __restrict__ b1,
    const float* __restrict__ m1, const float* __restrict__ v1,
    const float* __restrict__ gs, const float* __restrict__ bs,
    const float* __restrict__ ms, const float* __restrict__ vs,
    float* __restrict__ xbuf, float* __restrict__ scbuf)
{
    __shared__ float FsT[CIN][68];   // [k][row], pad 68 -> conflict-free b128 reads
    __shared__ float Wls[CIN][64];   // [k][c]
    const int t  = threadIdx.x;
    const int n0 = blockIdx.x * 64;
    const int by = blockIdx.y;

    // stage features tile 64 rows x 128 cols (transposed into LDS)
    {
        const float4* src = (const float4*)(F + (size_t)n0 * CIN);
        #pragma unroll
        for (int i = 0; i < 8; ++i) {
            int f = t + 256 * i;          // f4 index; row = f/32, c4 = f%32
            int row = f >> 5, c4 = f & 31;
            float4 v = src[f];
            FsT[c4 * 4 + 0][row] = v.x;
            FsT[c4 * 4 + 1][row] = v.y;
            FsT[c4 * 4 + 2][row] = v.z;
            FsT[c4 * 4 + 3][row] = v.w;
        }
    }
    // stage weight tile 128 x 64
    {
        const float* wsrc; int ld;
        if (by == 0) { wsrc = W1; ld = MID; }
        else         { wsrc = Ws + (by - 1) * 64; ld = COUT; }
        #pragma unroll
        for (int i = 0; i < 8; ++i) {
            int f = t + 256 * i;          // row = f/16, c4 = f%16
            int row = f >> 4, c4 = f & 15;
            float4 v = *(const float4*)(wsrc + (size_t)row * ld + c4 * 4);
            *(float4*)&Wls[row][c4 * 4] = v;
        }
    }
    __syncthreads();

    const int tx = t & 15, ty = t >> 4;
    float acc[4][4] = {};
    #pragma unroll 8
    for (int k = 0; k < CIN; ++k) {
        float4 a = *(const float4*)&FsT[k][ty * 4];
        float4 b = *(const float4*)&Wls[k][tx * 4];
        const float av[4] = {a.x, a.y, a.z, a.w};
        const float bv[4] = {b.x, b.y, b.z, b.w};
        #pragma unroll
        for (int i = 0; i < 4; ++i)
            #pragma unroll
            for (int j = 0; j < 4; ++j)
                acc[i][j] += av[i] * bv[j];
    }

    const float *gp, *bp, *mp, *vp;
    float* dst; int ldd, cbase;
    if (by == 0) { gp = g1; bp = b1; mp = m1; vp = v1; dst = xbuf;  ldd = MID;  cbase = 0; }
    else         { gp = gs; bp = bs; mp = ms; vp = vs; dst = scbuf; ldd = COUT; cbase = (by - 1) * 64; }

    float scale[4], shift[4];
    #pragma unroll
    for (int j = 0; j < 4; ++j) {
        int c = cbase + tx * 4 + j;
        float s = gp[c] / sqrtf(vp[c] + EPSBN);
        scale[j] = s;
        shift[j] = bp[c] - mp[c] * s;
    }
    #pragma unroll
    for (int i = 0; i < 4; ++i) {
        int row = n0 + ty * 4 + i;
        float4 o;
        o.x = lrelu(acc[i][0] * scale[0] + shift[0]);
        o.y = lrelu(acc[i][1] * scale[1] + shift[1]);
        o.z = lrelu(acc[i][2] * scale[2] + shift[2]);
        o.w = lrelu(acc[i][3] * scale[3] + shift[3]);
        *(float4*)(dst + (size_t)row * ldd + cbase + tx * 4) = o;
    }
}

// ---------------------------------------------------------------------------
// K2: KPConv influence + weighted gather.
// One wave per point (block = 256 = 4 waves = 4 points). lane = channel.
// h[k][p] computed cooperatively into LDS (pad 20 -> aligned b128 broadcast
// reads, only 4-way write conflicts), then per-k gather-FMA into 15 regs.
// Writes wf n-major: wf[n][p*64 + c]  (so K3 is a plain K=960 GEMM).
// ---------------------------------------------------------------------------
__global__ __launch_bounds__(256) void k2_wf(
    const float* __restrict__ xbuf,
    const float* __restrict__ pts,
    const int* __restrict__ nidx,
    const float* __restrict__ kpp,
    float* __restrict__ wf)
{
    __shared__ float h_lds[4][KNB][20];
    __shared__ int   ni_lds[4][KNB];
    __shared__ float kp_lds[PKP * 3];
    const int t = threadIdx.x;
    const int w = t >> 6, lane = t & 63;
    const int n = blockIdx.x * 4 + w;

    if (t < PKP * 3) kp_lds[t] = kpp[t];
    if (lane < KNB)  ni_lds[w][lane] = nidx[(size_t)n * KNB + lane];
    __syncthreads();

    // h production: lane -> (p = lane&15, kgroup = lane>>4), 8 k's per lane
    {
        const int p = lane & 15, kg = lane >> 4;
        float kx = 0.f, ky = 0.f, kz = 0.f;
        if (p < PKP) { kx = kp_lds[p * 3]; ky = kp_lds[p * 3 + 1]; kz = kp_lds[p * 3 + 2]; }
        const float cx = pts[(size_t)n * 3];
        const float cy = pts[(size_t)n * 3 + 1];
        const float cz = pts[(size_t)n * 3 + 2];
        #pragma unroll
        for (int j = 0; j < 8; ++j) {
            int kk = kg * 8 + j;
            int nb = ni_lds[w][kk];
            // match reference order: (pts[nb]-center) - kernel_point
            float ex = (pts[(size_t)nb * 3]     - cx) - kx;
            float ey = (pts[(size_t)nb * 3 + 1] - cy) - ky;
            float ez = (pts[(size_t)nb * 3 + 2] - cz) - kz;
            float dist = sqrtf(ex * ex + ey * ey + ez * ez);
            float hv = fmaxf(0.0f, 1.0f - dist * 20.0f);   // 1/KP_EXTENT == 20.0f exactly
            if (p < PKP) h_lds[w][kk][p] = hv;
        }
    }
    __syncthreads();

    // wf accumulation: lane = channel c
    float wfacc[PKP];
    #pragma unroll
    for (int p = 0; p < PKP; ++p) wfacc[p] = 0.f;

    for (int kk = 0; kk < KNB; ++kk) {
        int nb = ni_lds[w][kk];
        float f = xbuf[(size_t)nb * MID + lane];
        float4 h0 = *(const float4*)&h_lds[w][kk][0];
        float4 h1 = *(const float4*)&h_lds[w][kk][4];
        float4 h2 = *(const float4*)&h_lds[w][kk][8];
        float4 h3 = *(const float4*)&h_lds[w][kk][12];
        wfacc[0]  += h0.x * f;  wfacc[1]  += h0.y * f;
        wfacc[2]  += h0.z * f;  wfacc[3]  += h0.w * f;
        wfacc[4]  += h1.x * f;  wfacc[5]  += h1.y * f;
        wfacc[6]  += h1.z * f;  wfacc[7]  += h1.w * f;
        wfacc[8]  += h2.x * f;  wfacc[9]  += h2.y * f;
        wfacc[10] += h2.z * f;  wfacc[11] += h2.w * f;
        wfacc[12] += h3.x * f;  wfacc[13] += h3.y * f;
        wfacc[14] += h3.z * f;
    }
    float* dst = wf + (size_t)n * (PKP * MID);
    #pragma unroll
    for (int p = 0; p < PKP; ++p) dst[p * MID + lane] = wfacc[p];
}

// ---------------------------------------------------------------------------
// K3: y = lrelu( wf[N,960] @ Wkp[960,64] )  -> ybuf[N,64]
// 64x64 tile, 256 threads, 4x4/thread, K staged in 64-chunks.
// ---------------------------------------------------------------------------
__global__ __launch_bounds__(256) void k3_ygemm(
    const float* __restrict__ wf,
    const float* __restrict__ Wkp,
    float* __restrict__ ybuf)
{
    __shared__ float AsT[64][68];   // [k][row]
    __shared__ float Bs[64][64];    // [k][c]
    const int t  = threadIdx.x;
    const int n0 = blockIdx.x * 64;
    const int tx = t & 15, ty = t >> 4;
    float acc[4][4] = {};

    for (int kc = 0; kc < PKP * MID; kc += 64) {
        #pragma unroll
        for (int i = 0; i < 4; ++i) {
            int f = t + 256 * i;
            int row = f >> 4, c4 = f & 15;
            float4 v = *(const float4*)(wf + (size_t)(n0 + row) * (PKP * MID) + kc + c4 * 4);
            AsT[c4 * 4 + 0][row] = v.x;
            AsT[c4 * 4 + 1][row] = v.y;
            AsT[c4 * 4 + 2][row] = v.z;
            AsT[c4 * 4 + 3][row] = v.w;
        }
        #pragma unroll
        for (int i = 0; i < 4; ++i) {
            int f = t + 256 * i;
            int row = f >> 4, c4 = f & 15;
            *(float4*)&Bs[row][c4 * 4] = *(const float4*)(Wkp + (size_t)(kc + row) * MID + c4 * 4);
        }
        __syncthreads();
        #pragma unroll 8
        for (int k = 0; k < 64; ++k) {
            float4 a = *(const float4*)&AsT[k][ty * 4];
            float4 b = *(const float4*)&Bs[k][tx * 4];
            const float av[4] = {a.x, a.y, a.z, a.w};
            const float bv[4] = {b.x, b.y, b.z, b.w};
            #pragma unroll
            for (int i = 0; i < 4; ++i)
                #pragma unroll
                for (int j = 0; j < 4; ++j)
                    acc[i][j] += av[i] * bv[j];
        }
        __syncthreads();
    }
    #pragma unroll
    for (int i = 0; i < 4; ++i) {
        int row = n0 + ty * 4 + i;
        float4 o;
        o.x = lrelu(acc[i][0]);
        o.y = lrelu(acc[i][1]);
        o.z = lrelu(acc[i][2]);
        o.w = lrelu(acc[i][3]);
        *(float4*)(ybuf + (size_t)row * MID + tx * 4) = o;
    }
}

// ---------------------------------------------------------------------------
// K4: out = lrelu( lrelu(bn2(ybuf @ W2)) + scbuf )   [N,256]
// grid (N/64, 4): 64x64 tile of the 256 output cols; K=64 staged once.
// ---------------------------------------------------------------------------
__global__ __launch_bounds__(256) void k4_tail(
    const float* __restrict__ ybuf,
    const float* __restrict__ W2,
    const float* __restrict__ g2, const float* __restrict__ b2,
    const float* __restrict__ m2, const float* __restrict__ v2,
    const float* __restrict__ scbuf,
    float* __restrict__ out)
{
    __shared__ float AsT[MID][68];  // [k][row]
    __shared__ float Bs[MID][64];   // [k][c]
    const int t  = threadIdx.x;
    const int n0 = blockIdx.x * 64;
    const int c0 = blockIdx.y * 64;
    const int tx = t & 15, ty = t >> 4;

    #pragma unroll
    for (int i = 0; i < 4; ++i) {
        int f = t + 256 * i;
        int row = f >> 4, c4 = f & 15;
        float4 v = *(const float4*)(ybuf + (size_t)(n0 + row) * MID + c4 * 4);
        AsT[c4 * 4 + 0][row] = v.x;
        AsT[c4 * 4 + 1][row] = v.y;
        AsT[c4 * 4 + 2][row] = v.z;
        AsT[c4 * 4 + 3][row] = v.w;
    }
    #pragma unroll
    for (int i = 0; i < 4; ++i) {
        int f = t + 256 * i;
        int row = f >> 4, c4 = f & 15;
        *(float4*)&Bs[row][c4 * 4] = *(const float4*)(W2 + (size_t)row * COUT + c0 + c4 * 4);
    }
    __syncthreads();

    float acc[4][4] = {};
    #pragma unroll 8
    for (int k = 0; k < MID; ++k) {
        float4 a = *(const float4*)&AsT[k][ty * 4];
        float4 b = *(const float4*)&Bs[k][tx * 4];
        const float av[4] = {a.x, a.y, a.z, a.w};
        const float bv[4] = {b.x, b.y, b.z, b.w};
        #pragma unroll
        for (int i = 0; i < 4; ++i)
            #pragma unroll
            for (int j = 0; j < 4; ++j)
                acc[i][j] += av[i] * bv[j];
    }

    float scale[4], shift[4];
    #pragma unroll
    for (int j = 0; j < 4; ++j) {
        int c = c0 + tx * 4 + j;
        float s = g2[c] / sqrtf(v2[c] + EPSBN);
        scale[j] = s;
        shift[j] = b2[c] - m2[c] * s;
    }
    #pragma unroll
    for (int i = 0; i < 4; ++i) {
        int row = n0 + ty * 4 + i;
        float4 sc4 = *(const float4*)(scbuf + (size_t)row * COUT + c0 + tx * 4);
        float4 o;
        o.x = lrelu(lrelu(acc[i][0] * scale[0] + shift[0]) + sc4.x);
        o.y = lrelu(lrelu(acc[i][1] * scale[1] + shift[1]) + sc4.y);
        o.z = lrelu(lrelu(acc[i][2] * scale[2] + shift[2]) + sc4.z);
        o.w = lrelu(lrelu(acc[i][3] * scale[3] + shift[3]) + sc4.w);
        *(float4*)(out + (size_t)row * COUT + c0 + tx * 4) = o;
    }
}

// ---------------------------------------------------------------------------
extern "C" void kernel_launch(void* const* d_in, const int* in_sizes, int n_in,
                              void* d_out, int out_size, void* d_ws, size_t ws_size,
                              hipStream_t stream)
{
    const float* F   = (const float*)d_in[0];
    const float* pts = (const float*)d_in[1];
    const int*   nid = (const int*)d_in[2];
    const float* W1  = (const float*)d_in[3];
    const float* g1  = (const float*)d_in[4];
    const float* b1  = (const float*)d_in[5];
    const float* m1  = (const float*)d_in[6];
    const float* v1  = (const float*)d_in[7];
    const float* kpp = (const float*)d_in[8];
    const float* Wkp = (const float*)d_in[9];
    const float* W2  = (const float*)d_in[10];
    const float* g2  = (const float*)d_in[11];
    const float* b2  = (const float*)d_in[12];
    const float* m2  = (const float*)d_in[13];
    const float* v2  = (const float*)d_in[14];
    const float* Ws  = (const float*)d_in[15];
    const float* gs  = (const float*)d_in[16];
    const float* bs  = (const float*)d_in[17];
    const float* ms  = (const float*)d_in[18];
    const float* vs  = (const float*)d_in[19];

    const int N = in_sizes[0] / CIN;   // 40000

    float* xbuf  = (float*)d_ws;                   // [N,64]; reused as ybuf after K2
    float* scbuf = xbuf  + (size_t)N * MID;        // [N,256]
    float* wfbuf = scbuf + (size_t)N * COUT;       // [N,960]
    float* ybuf  = xbuf;                           // alias: xbuf dead after K2
    float* out   = (float*)d_out;

    k1_pointwise<<<dim3(N / 64, 5), 256, 0, stream>>>(
        F, W1, Ws, g1, b1, m1, v1, gs, bs, ms, vs, xbuf, scbuf);
    k2_wf<<<dim3(N / 4), 256, 0, stream>>>(xbuf, pts, nid, kpp, wfbuf);
    k3_ygemm<<<dim3(N / 64), 256, 0, stream>>>(wfbuf, Wkp, ybuf);
    k4_tail<<<dim3(N / 64, 4), 256, 0, stream>>>(
        ybuf, W2, g2, b2, m2, v2, scbuf, out);
}

// Round 3
// 290.819 us; speedup vs baseline: 1.2414x; 1.2414x over previous
//
#include <hip/hip_runtime.h>
#include <math.h>

#define EPSBN 1e-5f

constexpr int CIN  = 128;
constexpr int MID  = 64;
constexpr int COUT = 256;
constexpr int KNB  = 32;
constexpr int PKP  = 15;

typedef __bf16 v8bf  __attribute__((ext_vector_type(8)));
typedef float  f32x4 __attribute__((ext_vector_type(4)));

__device__ __forceinline__ float lrelu(float x) { return x >= 0.0f ? x : 0.1f * x; }

// round-to-nearest-even fp32 -> bf16 (bit trick)
__device__ __forceinline__ unsigned bf16_rne(float f) {
    unsigned u = __float_as_uint(f);
    return (u + 0x7fffu + ((u >> 16) & 1u)) >> 16;
}

// split 8 floats into hi/lo bf16x8 fragments (error-compensated split)
__device__ __forceinline__ void split_pack8(const float* s, v8bf& hi, v8bf& lo) {
    unsigned h[8], l[8];
    #pragma unroll
    for (int j = 0; j < 8; ++j) {
        float a = s[j];
        unsigned hu = bf16_rne(a);
        float r = a - __uint_as_float(hu << 16);
        h[j] = hu;
        l[j] = bf16_rne(r);
    }
    union { uint4 u; v8bf v; } H, L;
    H.u = make_uint4(h[0] | (h[1] << 16), h[2] | (h[3] << 16),
                     h[4] | (h[5] << 16), h[6] | (h[7] << 16));
    L.u = make_uint4(l[0] | (l[1] << 16), l[2] | (l[3] << 16),
                     l[4] | (l[5] << 16), l[6] | (l[7] << 16));
    hi = H.v;
    lo = L.v;
}

__device__ __forceinline__ v8bf as_v8bf(uint4 u) {
    union { uint4 u; v8bf v; } X;
    X.u = u;
    return X.v;
}

// ---------------------------------------------------------------------------
// prep: pack weights into MFMA B-fragment order (hi/lo bf16), precompute BN.
// B-frag convention: lane l holds B[k = kt*32+(l>>4)*8+j][col = nt*16+(l&15)],
// j=0..7 packed as one uint4 per lane. (A uses the same (lane,j)->k formula,
// so the contraction is invariant to the HW's intra-fragment k-permutation.)
//   Wkp: K=960, N=64  -> 30 kt x 4 nt  -> 7680 uint4 each (hi,lo)
//   Wc = [W1 | Ws]: K=128, N=320 -> 4 kt x 20 nt -> 5120 uint4 each
//   W2:  K=64,  N=256 -> 2 kt x 16 nt -> 2048 uint4 each
//   bnscale/bnshift[576]: 0..63 bn1, 64..319 bns, 320..575 bn2
// ---------------------------------------------------------------------------
__global__ __launch_bounds__(256) void prep(
    const float* __restrict__ Wkp, const float* __restrict__ W1,
    const float* __restrict__ Ws,  const float* __restrict__ W2,
    const float* __restrict__ g1, const float* __restrict__ b1,
    const float* __restrict__ m1, const float* __restrict__ v1,
    const float* __restrict__ gs, const float* __restrict__ bs,
    const float* __restrict__ ms, const float* __restrict__ vs,
    const float* __restrict__ g2, const float* __restrict__ b2,
    const float* __restrict__ m2, const float* __restrict__ v2,
    uint4* __restrict__ WkpPh, uint4* __restrict__ WkpPl,
    uint4* __restrict__ WcPh,  uint4* __restrict__ WcPl,
    uint4* __restrict__ W2Ph,  uint4* __restrict__ W2Pl,
    float* __restrict__ bnscale, float* __restrict__ bnshift)
{
    const int b = blockIdx.x, t = threadIdx.x;
    if (b < 30) {                       // Wkp pack
        int gt = b * 256 + t;           // [0,7680)
        int lane = gt & 63, rest = gt >> 6;
        int nt = rest & 3, kt = rest >> 2;
        int col = nt * 16 + (lane & 15);
        int kbase = kt * 32 + ((lane >> 4) << 3);
        float tmp[8];
        #pragma unroll
        for (int j = 0; j < 8; ++j)
            tmp[j] = Wkp[(size_t)(kbase + j) * MID + col];
        v8bf hi, lo;
        split_pack8(tmp, hi, lo);
        union { v8bf v; uint4 u; } H, L; H.v = hi; L.v = lo;
        WkpPh[gt] = H.u; WkpPl[gt] = L.u;
    } else if (b < 50) {                // Wc = [W1|Ws] pack
        int gt = (b - 30) * 256 + t;    // [0,5120)
        int lane = gt & 63, rest = gt >> 6;
        int kt = rest / 20, nt = rest % 20;
        int c = nt * 16 + (lane & 15);
        int kbase = kt * 32 + ((lane >> 4) << 3);
        float tmp[8];
        #pragma unroll
        for (int j = 0; j < 8; ++j) {
            int k = kbase + j;
            tmp[j] = (c < 64) ? W1[(size_t)k * MID + c]
                              : Ws[(size_t)k * COUT + (c - 64)];
        }
        v8bf hi, lo;
        split_pack8(tmp, hi, lo);
        union { v8bf v; uint4 u; } H, L; H.v = hi; L.v = lo;
        WcPh[gt] = H.u; WcPl[gt] = L.u;
    } else if (b < 58) {                // W2 pack
        int gt = (b - 50) * 256 + t;    // [0,2048)
        int lane = gt & 63, rest = gt >> 6;   // [0,32)
        int kt = rest >> 4, nt = rest & 15;
        int col = nt * 16 + (lane & 15);
        int kbase = kt * 32 + ((lane >> 4) << 3);
        float tmp[8];
        #pragma unroll
        for (int j = 0; j < 8; ++j)
            tmp[j] = W2[(size_t)(kbase + j) * COUT + col];
        v8bf hi, lo;
        split_pack8(tmp, hi, lo);
        union { v8bf v; uint4 u; } H, L; H.v = hi; L.v = lo;
        W2Ph[gt] = H.u; W2Pl[gt] = L.u;
    } else {                            // BN constants, 576 values
        int v = (b - 58) * 256 + t;
        if (v < 576) {
            float g, bb, mm, vv;
            if (v < 64)       { g = g1[v]; bb = b1[v]; mm = m1[v]; vv = v1[v]; }
            else if (v < 320) { int c = v - 64;  g = gs[c]; bb = bs[c]; mm = ms[c]; vv = vs[c]; }
            else              { int c = v - 320; g = g2[c]; bb = b2[c]; mm = m2[c]; vv = v2[c]; }
            float s = g / sqrtf(vv + EPSBN);
            bnscale[v] = s;
            bnshift[v] = bb - mm * s;
        }
    }
}

// ---------------------------------------------------------------------------
// K1 (MFMA): [64 rows x 128] @ [128 x 320] bf16x3, fused BN+lrelu epilogue.
// Cols 0..63 -> xbuf[N,64], cols 64..319 -> scbuf[N,256].
// ---------------------------------------------------------------------------
__global__ __launch_bounds__(256) void k1_mfma(
    const float* __restrict__ F,
    const uint4* __restrict__ WcPh, const uint4* __restrict__ WcPl,
    const float* __restrict__ bnscale, const float* __restrict__ bnshift,
    float* __restrict__ xbuf, float* __restrict__ scbuf)
{
    __shared__ float As[64][132];       // 132 % 32 == 4 -> cheap frag reads
    const int t = threadIdx.x;
    const int n0 = blockIdx.x * 64;

    const float4* src = (const float4*)(F + (size_t)n0 * CIN);
    #pragma unroll
    for (int i = 0; i < 8; ++i) {
        int idx = t + 256 * i;          // row = idx>>5, c4 = idx&31
        int row = idx >> 5, c4 = idx & 31;
        float4 v = src[idx];
        *(float4*)&As[row][c4 * 4] = v;
    }
    __syncthreads();

    const int l = t & 63, w = t >> 6;
    const int arow = w * 16 + (l & 15);
    const int k8 = (l >> 4) * 8;

    f32x4 acc[20];
    #pragma unroll
    for (int nt = 0; nt < 20; ++nt) acc[nt] = (f32x4){0.f, 0.f, 0.f, 0.f};

    #pragma unroll
    for (int kt = 0; kt < 4; ++kt) {
        float tmp[8];
        const float* ap = &As[arow][kt * 32 + k8];
        #pragma unroll
        for (int j = 0; j < 8; ++j) tmp[j] = ap[j];
        v8bf ah, al;
        split_pack8(tmp, ah, al);
        #pragma unroll
        for (int nt = 0; nt < 20; ++nt) {
            int bidx = ((kt * 20 + nt) << 6) + l;
            v8bf bh = as_v8bf(WcPh[bidx]);
            v8bf bl = as_v8bf(WcPl[bidx]);
            acc[nt] = __builtin_amdgcn_mfma_f32_16x16x32_bf16(ah, bh, acc[nt], 0, 0, 0);
            acc[nt] = __builtin_amdgcn_mfma_f32_16x16x32_bf16(al, bh, acc[nt], 0, 0, 0);
            acc[nt] = __builtin_amdgcn_mfma_f32_16x16x32_bf16(ah, bl, acc[nt], 0, 0, 0);
        }
    }

    const int colr = l & 15;
    const int rq = (l >> 4) * 4;
    #pragma unroll
    for (int nt = 0; nt < 20; ++nt) {
        int col = nt * 16 + colr;
        float sc = bnscale[col], sh = bnshift[col];
        #pragma unroll
        for (int r = 0; r < 4; ++r) {
            int row = n0 + w * 16 + rq + r;
            float val = lrelu(acc[nt][r] * sc + sh);
            if (col < 64) xbuf [(size_t)row * MID  + col]        = val;
            else          scbuf[(size_t)row * COUT + (col - 64)] = val;
        }
    }
}

// ---------------------------------------------------------------------------
// K23 (fused KPConv + GEMM): block = 16 points, 4 waves.
// Phase 1 (exact fp32): wave w gathers/accumulates wf for points w*4..w*4+3
//   into LDS wfs[16][960(+4)] (k = p*64 + c).
// Phase 2: y[16,64] = wf @ Wkp via bf16x3 MFMA, lrelu -> ybuf[N,64].
// ---------------------------------------------------------------------------
__global__ __launch_bounds__(256) void k23_fused(
    const float* __restrict__ xbuf,
    const float* __restrict__ pts,
    const int* __restrict__ nidx,
    const float* __restrict__ kpp,
    const uint4* __restrict__ WkpPh, const uint4* __restrict__ WkpPl,
    float* __restrict__ ybuf)
{
    __shared__ float wfs[16][964];      // 964 % 32 == 4
    __shared__ float hs[4][KNB][16];
    __shared__ int   nis[16][KNB];
    __shared__ float kps[PKP * 3];

    const int t = threadIdx.x;
    const int l = t & 63, w = t >> 6;
    const int n0 = blockIdx.x * 16;

    if (t < PKP * 3) kps[t] = kpp[t];
    {
        int i1 = t, i2 = t + 256;
        nis[i1 >> 5][i1 & 31] = nidx[(size_t)n0 * KNB + i1];
        nis[i2 >> 5][i2 & 31] = nidx[(size_t)n0 * KNB + i2];
    }
    __syncthreads();

    // ---- phase 1 ----
    for (int pt = 0; pt < 4; ++pt) {
        const int pl = w * 4 + pt;      // local point 0..15
        const int n  = n0 + pl;
        // h[k][p] cooperative compute: lane -> (p = l&15, kgroup = l>>4)
        {
            const int p = l & 15, kg = l >> 4;
            float kx = 0.f, ky = 0.f, kz = 0.f;
            if (p < PKP) { kx = kps[p * 3]; ky = kps[p * 3 + 1]; kz = kps[p * 3 + 2]; }
            const float cx = pts[(size_t)n * 3];
            const float cy = pts[(size_t)n * 3 + 1];
            const float cz = pts[(size_t)n * 3 + 2];
            #pragma unroll
            for (int j = 0; j < 8; ++j) {
                int kk = kg * 8 + j;
                int nb = nis[pl][kk];
                float ex = (pts[(size_t)nb * 3]     - cx) - kx;
                float ey = (pts[(size_t)nb * 3 + 1] - cy) - ky;
                float ez = (pts[(size_t)nb * 3 + 2] - cz) - kz;
                float dist = sqrtf(ex * ex + ey * ey + ez * ez);
                float hv = fmaxf(0.0f, 1.0f - dist * 20.0f);
                if (p < PKP) hs[w][kk][p] = hv;
            }
        }
        __syncthreads();

        // gather: issue all 32 feature loads up-front (lane = channel)
        float fv[KNB];
        #pragma unroll
        for (int kk = 0; kk < KNB; ++kk)
            fv[kk] = xbuf[(size_t)nis[pl][kk] * MID + l];

        float wfacc[PKP];
        #pragma unroll
        for (int p = 0; p < PKP; ++p) wfacc[p] = 0.f;

        #pragma unroll
        for (int kk = 0; kk < KNB; ++kk) {
            float4 h0 = *(const float4*)&hs[w][kk][0];
            float4 h1 = *(const float4*)&hs[w][kk][4];
            float4 h2 = *(const float4*)&hs[w][kk][8];
            float4 h3 = *(const float4*)&hs[w][kk][12];
            float f = fv[kk];
            wfacc[0]  += h0.x * f;  wfacc[1]  += h0.y * f;
            wfacc[2]  += h0.z * f;  wfacc[3]  += h0.w * f;
            wfacc[4]  += h1.x * f;  wfacc[5]  += h1.y * f;
            wfacc[6]  += h1.z * f;  wfacc[7]  += h1.w * f;
            wfacc[8]  += h2.x * f;  wfacc[9]  += h2.y * f;
            wfacc[10] += h2.z * f;  wfacc[11] += h2.w * f;
            wfacc[12] += h3.x * f;  wfacc[13] += h3.y * f;
            wfacc[14] += h3.z * f;
        }
        #pragma unroll
        for (int p = 0; p < PKP; ++p)
            wfs[pl][p * MID + l] = wfacc[p];
        __syncthreads();
    }
    __syncthreads();

    // ---- phase 2: y = wf @ Wkp (K=960), wave w owns n-tile w ----
    const int nt = w;
    const int arow = l & 15;
    const int k8 = (l >> 4) * 8;
    f32x4 a0 = {0.f, 0.f, 0.f, 0.f};
    f32x4 a1 = {0.f, 0.f, 0.f, 0.f};
    f32x4 a2 = {0.f, 0.f, 0.f, 0.f};

    #pragma unroll
    for (int kt = 0; kt < 30; ++kt) {
        float tmp[8];
        const float* ap = &wfs[arow][kt * 32 + k8];
        #pragma unroll
        for (int j = 0; j < 8; ++j) tmp[j] = ap[j];
        v8bf ah, al;
        split_pack8(tmp, ah, al);
        int bidx = ((kt << 2) + nt) * 64 + l;
        v8bf bh = as_v8bf(WkpPh[bidx]);
        v8bf bl = as_v8bf(WkpPl[bidx]);
        a0 = __builtin_amdgcn_mfma_f32_16x16x32_bf16(ah, bh, a0, 0, 0, 0);
        a1 = __builtin_amdgcn_mfma_f32_16x16x32_bf16(al, bh, a1, 0, 0, 0);
        a2 = __builtin_amdgcn_mfma_f32_16x16x32_bf16(ah, bl, a2, 0, 0, 0);
    }

    const int col = nt * 16 + (l & 15);
    const int rq = (l >> 4) * 4;
    #pragma unroll
    for (int r = 0; r < 4; ++r) {
        int row = rq + r;
        float yv = lrelu(a0[r] + a1[r] + a2[r]);
        ybuf[(size_t)(n0 + row) * MID + col] = yv;
    }
}

// ---------------------------------------------------------------------------
// K4 (MFMA): out = lrelu( lrelu(bn2(ybuf @ W2)) + scbuf )   [N,256]
// 64-row block, 4 waves; K=64 (2 kt), 16 n-tiles; bf16x3; fused epilogue.
// ---------------------------------------------------------------------------
__global__ __launch_bounds__(256) void k4_mfma(
    const float* __restrict__ ybuf,
    const uint4* __restrict__ W2Ph, const uint4* __restrict__ W2Pl,
    const float* __restrict__ bnscale, const float* __restrict__ bnshift,
    const float* __restrict__ scbuf,
    float* __restrict__ out)
{
    __shared__ float As[64][68];        // 68 % 32 == 4
    const int t = threadIdx.x;
    const int n0 = blockIdx.x * 64;

    #pragma unroll
    for (int i = 0; i < 4; ++i) {
        int idx = t + 256 * i;          // row = idx>>4, c4 = idx&15
        int row = idx >> 4, c4 = idx & 15;
        float4 v = *(const float4*)(ybuf + (size_t)(n0 + row) * MID + c4 * 4);
        *(float4*)&As[row][c4 * 4] = v;
    }
    __syncthreads();

    const int l = t & 63, w = t >> 6;
    const int arow = w * 16 + (l & 15);
    const int k8 = (l >> 4) * 8;

    f32x4 acc[16];
    #pragma unroll
    for (int nt = 0; nt < 16; ++nt) acc[nt] = (f32x4){0.f, 0.f, 0.f, 0.f};

    #pragma unroll
    for (int kt = 0; kt < 2; ++kt) {
        float tmp[8];
        const float* ap = &As[arow][kt * 32 + k8];
        #pragma unroll
        for (int j = 0; j < 8; ++j) tmp[j] = ap[j];
        v8bf ah, al;
        split_pack8(tmp, ah, al);
        #pragma unroll
        for (int nt = 0; nt < 16; ++nt) {
            int bidx = (((kt << 4) + nt) << 6) + l;
            v8bf bh = as_v8bf(W2Ph[bidx]);
            v8bf bl = as_v8bf(W2Pl[bidx]);
            acc[nt] = __builtin_amdgcn_mfma_f32_16x16x32_bf16(ah, bh, acc[nt], 0, 0, 0);
            acc[nt] = __builtin_amdgcn_mfma_f32_16x16x32_bf16(al, bh, acc[nt], 0, 0, 0);
            acc[nt] = __builtin_amdgcn_mfma_f32_16x16x32_bf16(ah, bl, acc[nt], 0, 0, 0);
        }
    }

    const int colr = l & 15;
    const int rq = (l >> 4) * 4;
    #pragma unroll
    for (int nt = 0; nt < 16; ++nt) {
        int col = nt * 16 + colr;
        float sc = bnscale[320 + col], sh = bnshift[320 + col];
        #pragma unroll
        for (int r = 0; r < 4; ++r) {
            int row = n0 + w * 16 + rq + r;
            float val = lrelu(acc[nt][r] * sc + sh);
            float scv = scbuf[(size_t)row * COUT + col];
            out[(size_t)row * COUT + col] = lrelu(val + scv);
        }
    }
}

// ---------------------------------------------------------------------------
extern "C" void kernel_launch(void* const* d_in, const int* in_sizes, int n_in,
                              void* d_out, int out_size, void* d_ws, size_t ws_size,
                              hipStream_t stream)
{
    const float* F   = (const float*)d_in[0];
    const float* pts = (const float*)d_in[1];
    const int*   nid = (const int*)d_in[2];
    const float* W1  = (const float*)d_in[3];
    const float* g1  = (const float*)d_in[4];
    const float* b1  = (const float*)d_in[5];
    const float* m1  = (const float*)d_in[6];
    const float* v1  = (const float*)d_in[7];
    const float* kpp = (const float*)d_in[8];
    const float* Wkp = (const float*)d_in[9];
    const float* W2  = (const float*)d_in[10];
    const float* g2  = (const float*)d_in[11];
    const float* b2  = (const float*)d_in[12];
    const float* m2  = (const float*)d_in[13];
    const float* v2  = (const float*)d_in[14];
    const float* Ws  = (const float*)d_in[15];
    const float* gs  = (const float*)d_in[16];
    const float* bs  = (const float*)d_in[17];
    const float* ms  = (const float*)d_in[18];
    const float* vs  = (const float*)d_in[19];

    const int N = in_sizes[0] / CIN;   // 40000

    float* xbuf   = (float*)d_ws;                     // [N,64]
    float* scbuf  = xbuf  + (size_t)N * MID;          // [N,256]
    float* ybuf   = scbuf + (size_t)N * COUT;         // [N,64]
    uint4* WkpPh  = (uint4*)(ybuf + (size_t)N * MID); // 7680 x 16B
    uint4* WkpPl  = WkpPh + 7680;
    uint4* WcPh   = WkpPl + 7680;                     // 5120 x 16B
    uint4* WcPl   = WcPh + 5120;
    uint4* W2Ph   = WcPl + 5120;                      // 2048 x 16B
    uint4* W2Pl   = W2Ph + 2048;
    float* bnscale = (float*)(W2Pl + 2048);           // 576
    float* bnshift = bnscale + 576;
    float* out    = (float*)d_out;

    prep<<<61, 256, 0, stream>>>(Wkp, W1, Ws, W2,
                                 g1, b1, m1, v1, gs, bs, ms, vs, g2, b2, m2, v2,
                                 WkpPh, WkpPl, WcPh, WcPl, W2Ph, W2Pl,
                                 bnscale, bnshift);
    k1_mfma<<<N / 64, 256, 0, stream>>>(F, WcPh, WcPl, bnscale, bnshift, xbuf, scbuf);
    k23_fused<<<N / 16, 256, 0, stream>>>(xbuf, pts, nid, kpp, WkpPh, WkpPl, ybuf);
    k4_mfma<<<N / 64, 256, 0, stream>>>(ybuf, W2Ph, W2Pl, bnscale, bnshift, scbuf, out);
}

// Round 6
// 236.984 us; speedup vs baseline: 1.5234x; 1.2272x over previous
//
#include <hip/hip_runtime.h>
#include <math.h>

#define EPSBN 1e-5f

constexpr int CIN  = 128;
constexpr int MID  = 64;
constexpr int COUT = 256;
constexpr int KNB  = 32;
constexpr int PKP  = 15;

constexpr int PSTR = 72;           // wfs p-slot stride (elements); 2*72 B, 16B-aligned
constexpr int WROW = PKP * PSTR;   // 1080 elements per point-row
constexpr int YROW = 72;           // y row stride (elements)

typedef __bf16 v8bf  __attribute__((ext_vector_type(8)));
typedef float  f32x4 __attribute__((ext_vector_type(4)));

__device__ __forceinline__ float lrelu(float x) { return x >= 0.0f ? x : 0.1f * x; }

// ---- bf16 split helpers (native cvt; RNE; residual-compensated) ----
__device__ __forceinline__ void split1(float v, unsigned short& h, unsigned short& l) {
    __bf16 hb = (__bf16)v;
    float r = v - (float)hb;
    __bf16 lb = (__bf16)r;
    h = __builtin_bit_cast(unsigned short, hb);
    l = __builtin_bit_cast(unsigned short, lb);
}

__device__ __forceinline__ void split_frag8(const float* s, v8bf& hi, v8bf& lo) {
    #pragma unroll
    for (int j = 0; j < 8; ++j) {
        __bf16 hb = (__bf16)s[j];
        float r = s[j] - (float)hb;
        hi[j] = hb;
        lo[j] = (__bf16)r;
    }
}

__device__ __forceinline__ v8bf as_v8bf(uint4 u) {
    union { uint4 u; v8bf v; } X;
    X.u = u;
    return X.v;
}

// bit-trick split (used by prep only; proven)
__device__ __forceinline__ unsigned bf16_rne(float f) {
    unsigned u = __float_as_uint(f);
    return (u + 0x7fffu + ((u >> 16) & 1u)) >> 16;
}
__device__ __forceinline__ void split_pack8(const float* s, v8bf& hi, v8bf& lo) {
    unsigned h[8], l[8];
    #pragma unroll
    for (int j = 0; j < 8; ++j) {
        float a = s[j];
        unsigned hu = bf16_rne(a);
        float r = a - __uint_as_float(hu << 16);
        h[j] = hu;
        l[j] = bf16_rne(r);
    }
    union { uint4 u; v8bf v; } H, L;
    H.u = make_uint4(h[0] | (h[1] << 16), h[2] | (h[3] << 16),
                     h[4] | (h[5] << 16), h[6] | (h[7] << 16));
    L.u = make_uint4(l[0] | (l[1] << 16), l[2] | (l[3] << 16),
                     l[4] | (l[5] << 16), l[6] | (l[7] << 16));
    hi = H.v;
    lo = L.v;
}

// ---------------------------------------------------------------------------
// prep: pack weights into MFMA B-fragment order (hi/lo bf16), precompute BN.
// B-frag: lane l holds B[k = kt*32+(l>>4)*8+j][col = nt*16+(l&15)], one uint4.
//   Wkp: 30 kt x 4 nt -> 7680 uint4 each; Wc=[W1|Ws]: 4 kt x 20 nt -> 5120;
//   W2: 2 kt x 16 nt -> 2048; bnscale/bnshift[576]: bn1, bns, bn2.
// ---------------------------------------------------------------------------
__global__ __launch_bounds__(256) void prep(
    const float* __restrict__ Wkp, const float* __restrict__ W1,
    const float* __restrict__ Ws,  const float* __restrict__ W2,
    const float* __restrict__ g1, const float* __restrict__ b1,
    const float* __restrict__ m1, const float* __restrict__ v1,
    const float* __restrict__ gs, const float* __restrict__ bs,
    const float* __restrict__ ms, const float* __restrict__ vs,
    const float* __restrict__ g2, const float* __restrict__ b2,
    const float* __restrict__ m2, const float* __restrict__ v2,
    uint4* __restrict__ WkpPh, uint4* __restrict__ WkpPl,
    uint4* __restrict__ WcPh,  uint4* __restrict__ WcPl,
    uint4* __restrict__ W2Ph,  uint4* __restrict__ W2Pl,
    float* __restrict__ bnscale, float* __restrict__ bnshift)
{
    const int b = blockIdx.x, t = threadIdx.x;
    if (b < 30) {                       // Wkp pack
        int gt = b * 256 + t;
        int lane = gt & 63, rest = gt >> 6;
        int nt = rest & 3, kt = rest >> 2;
        int col = nt * 16 + (lane & 15);
        int kbase = kt * 32 + ((lane >> 4) << 3);
        float tmp[8];
        #pragma unroll
        for (int j = 0; j < 8; ++j)
            tmp[j] = Wkp[(size_t)(kbase + j) * MID + col];
        v8bf hi, lo;
        split_pack8(tmp, hi, lo);
        union { v8bf v; uint4 u; } H, L; H.v = hi; L.v = lo;
        WkpPh[gt] = H.u; WkpPl[gt] = L.u;
    } else if (b < 50) {                // Wc = [W1|Ws] pack
        int gt = (b - 30) * 256 + t;
        int lane = gt & 63, rest = gt >> 6;
        int kt = rest / 20, nt = rest % 20;
        int c = nt * 16 + (lane & 15);
        int kbase = kt * 32 + ((lane >> 4) << 3);
        float tmp[8];
        #pragma unroll
        for (int j = 0; j < 8; ++j) {
            int k = kbase + j;
            tmp[j] = (c < 64) ? W1[(size_t)k * MID + c]
                              : Ws[(size_t)k * COUT + (c - 64)];
        }
        v8bf hi, lo;
        split_pack8(tmp, hi, lo);
        union { v8bf v; uint4 u; } H, L; H.v = hi; L.v = lo;
        WcPh[gt] = H.u; WcPl[gt] = L.u;
    } else if (b < 58) {                // W2 pack
        int gt = (b - 50) * 256 + t;
        int lane = gt & 63, rest = gt >> 6;
        int kt = rest >> 4, nt = rest & 15;
        int col = nt * 16 + (lane & 15);
        int kbase = kt * 32 + ((lane >> 4) << 3);
        float tmp[8];
        #pragma unroll
        for (int j = 0; j < 8; ++j)
            tmp[j] = W2[(size_t)(kbase + j) * COUT + col];
        v8bf hi, lo;
        split_pack8(tmp, hi, lo);
        union { v8bf v; uint4 u; } H, L; H.v = hi; L.v = lo;
        W2Ph[gt] = H.u; W2Pl[gt] = L.u;
    } else {                            // BN constants, 576 values
        int v = (b - 58) * 256 + t;
        if (v < 576) {
            float g, bb, mm, vv;
            if (v < 64)       { g = g1[v]; bb = b1[v]; mm = m1[v]; vv = v1[v]; }
            else if (v < 320) { int c = v - 64;  g = gs[c]; bb = bs[c]; mm = ms[c]; vv = vs[c]; }
            else              { int c = v - 320; g = g2[c]; bb = b2[c]; mm = m2[c]; vv = v2[c]; }
            float s = g / sqrtf(vv + EPSBN);
            bnscale[v] = s;
            bnshift[v] = bb - mm * s;
        }
    }
}

// ---------------------------------------------------------------------------
// K1 (MFMA): [64 x 128] @ [128 x 320] bf16x3 + BN + lrelu.
// Cols 0..63 -> xp[N,64] PACKED (hi<<16|lo) bf16 pair per channel;
// cols 64..319 -> scbuf[N,256] f32.
// ---------------------------------------------------------------------------
__global__ __launch_bounds__(256) void k1_mfma(
    const float* __restrict__ F,
    const uint4* __restrict__ WcPh, const uint4* __restrict__ WcPl,
    const float* __restrict__ bnscale, const float* __restrict__ bnshift,
    unsigned* __restrict__ xp, float* __restrict__ scbuf)
{
    __shared__ float As[64][132];       // 132 % 32 == 4
    const int t = threadIdx.x;
    const int n0 = blockIdx.x * 64;

    const float4* src = (const float4*)(F + (size_t)n0 * CIN);
    #pragma unroll
    for (int i = 0; i < 8; ++i) {
        int idx = t + 256 * i;
        int row = idx >> 5, c4 = idx & 31;
        float4 v = src[idx];
        *(float4*)&As[row][c4 * 4] = v;
    }
    __syncthreads();

    const int l = t & 63, w = t >> 6;
    const int arow = w * 16 + (l & 15);
    const int k8 = (l >> 4) * 8;

    f32x4 acc[20];
    #pragma unroll
    for (int nt = 0; nt < 20; ++nt) acc[nt] = (f32x4){0.f, 0.f, 0.f, 0.f};

    #pragma unroll
    for (int kt = 0; kt < 4; ++kt) {
        float tmp[8];
        const float* ap = &As[arow][kt * 32 + k8];
        #pragma unroll
        for (int j = 0; j < 8; ++j) tmp[j] = ap[j];
        v8bf ah, al;
        split_frag8(tmp, ah, al);
        #pragma unroll
        for (int nt = 0; nt < 20; ++nt) {
            int bidx = ((kt * 20 + nt) << 6) + l;
            v8bf bh = as_v8bf(WcPh[bidx]);
            v8bf bl = as_v8bf(WcPl[bidx]);
            acc[nt] = __builtin_amdgcn_mfma_f32_16x16x32_bf16(ah, bh, acc[nt], 0, 0, 0);
            acc[nt] = __builtin_amdgcn_mfma_f32_16x16x32_bf16(al, bh, acc[nt], 0, 0, 0);
            acc[nt] = __builtin_amdgcn_mfma_f32_16x16x32_bf16(ah, bl, acc[nt], 0, 0, 0);
        }
    }

    const int colr = l & 15;
    const int rq = (l >> 4) * 4;
    #pragma unroll
    for (int nt = 0; nt < 20; ++nt) {
        int col = nt * 16 + colr;
        float sc = bnscale[col], sh = bnshift[col];
        #pragma unroll
        for (int r = 0; r < 4; ++r) {
            int row = n0 + w * 16 + rq + r;
            float val = lrelu(acc[nt][r] * sc + sh);
            if (col < 64) {
                unsigned short hu, lu;
                split1(val, hu, lu);
                xp[(size_t)row * MID + col] = ((unsigned)hu << 16) | lu;
            } else {
                scbuf[(size_t)row * COUT + (col - 64)] = val;
            }
        }
    }
}

// ---------------------------------------------------------------------------
// K234 (fused KPConv-MFMA + y-GEMM + tail-GEMM): block = 16 points, 4 waves.
// Phase 1: per point, wf = h^T[16x32] @ f[32x64] via bf16x3 MFMA.
//   h built directly in A-frag layout in regs (p = l&15, k = (l>>4)*8+j);
//   f gathered as packed (hi|lo) dwords from xp, repacked to B-frags.
//   D split to bf16 hi/lo and stored to wfsH/wfsL (k-contiguous, PSTR=72).
// Phase 2: y[16,64] = wf @ Wkp, K=960; A-frags are single b128 reads (no split).
// Phase 3: out = lrelu(lrelu(bn2(y @ W2)) + sc), K=64, fused epilogue.
// ---------------------------------------------------------------------------
__global__ __launch_bounds__(256) void k234_fused(
    const unsigned* __restrict__ xp,
    const float* __restrict__ pts,
    const int* __restrict__ nidx,
    const float* __restrict__ kpp,
    const uint4* __restrict__ WkpPh, const uint4* __restrict__ WkpPl,
    const uint4* __restrict__ W2Ph,  const uint4* __restrict__ W2Pl,
    const float* __restrict__ bnscale, const float* __restrict__ bnshift,
    const float* __restrict__ scbuf,
    float* __restrict__ out)
{
    __shared__ unsigned short wfsH[16 * WROW];   // 33.75 KB
    __shared__ unsigned short wfsL[16 * WROW];   // 33.75 KB
    __shared__ unsigned short yH[16 * YROW];     // 2.25 KB
    __shared__ unsigned short yL[16 * YROW];     // 2.25 KB

    const int t = threadIdx.x;
    const int l = t & 63, w = t >> 6;
    const int col = l & 15, kg = l >> 4;
    const int k8 = kg * 8;
    const int n0 = blockIdx.x * 16;

    // kernel point for this lane's A-row (p = col); p==15 -> h = 0
    float kx = 0.f, ky = 0.f, kz = 0.f;
    if (col < PKP) { kx = kpp[col * 3]; ky = kpp[col * 3 + 1]; kz = kpp[col * 3 + 2]; }

    // ---- phase 1: per-point KPConv via MFMA ----
    for (int pt = 0; pt < 4; ++pt) {
        const int pl = w * 4 + pt;
        const int n  = n0 + pl;
        const float cx = pts[(size_t)n * 3];
        const float cy = pts[(size_t)n * 3 + 1];
        const float cz = pts[(size_t)n * 3 + 2];
        const int4 nba = ((const int4*)nidx)[(size_t)n * 8 + kg * 2];
        const int4 nbb = ((const int4*)nidx)[(size_t)n * 8 + kg * 2 + 1];
        int nb[8] = {nba.x, nba.y, nba.z, nba.w, nbb.x, nbb.y, nbb.z, nbb.w};

        // gather packed features: u[j][nt] covers B[k=k8+j][c=nt*16+col]
        unsigned u[8][4];
        #pragma unroll
        for (int j = 0; j < 8; ++j) {
            const unsigned* xr = xp + (size_t)nb[j] * MID + col;
            u[j][0] = xr[0];
            u[j][1] = xr[16];
            u[j][2] = xr[32];
            u[j][3] = xr[48];
        }

        // influence h for (p=col, k=k8+j) -> A-fragment
        float hv[8];
        #pragma unroll
        for (int j = 0; j < 8; ++j) {
            float ex = (pts[(size_t)nb[j] * 3]     - cx) - kx;
            float ey = (pts[(size_t)nb[j] * 3 + 1] - cy) - ky;
            float ez = (pts[(size_t)nb[j] * 3 + 2] - cz) - kz;
            float dist = sqrtf(ex * ex + ey * ey + ez * ez);
            float h = fmaxf(0.0f, 1.0f - dist * 20.0f);   // 1/KP_EXTENT
            hv[j] = (col < PKP) ? h : 0.0f;
        }
        v8bf ah, al;
        split_frag8(hv, ah, al);

        #pragma unroll
        for (int nt = 0; nt < 4; ++nt) {
            unsigned bhW[4], blW[4];
            #pragma unroll
            for (int i = 0; i < 4; ++i) {
                unsigned u0 = u[2 * i][nt], u1 = u[2 * i + 1][nt];
                bhW[i] = (u1 & 0xFFFF0000u) | (u0 >> 16);
                blW[i] = (u1 << 16) | (u0 & 0xFFFFu);
            }
            v8bf bh = as_v8bf(make_uint4(bhW[0], bhW[1], bhW[2], bhW[3]));
            v8bf bl = as_v8bf(make_uint4(blW[0], blW[1], blW[2], blW[3]));
            f32x4 acc = {0.f, 0.f, 0.f, 0.f};
            acc = __builtin_amdgcn_mfma_f32_16x16x32_bf16(ah, bh, acc, 0, 0, 0);
            acc = __builtin_amdgcn_mfma_f32_16x16x32_bf16(al, bh, acc, 0, 0, 0);
            acc = __builtin_amdgcn_mfma_f32_16x16x32_bf16(ah, bl, acc, 0, 0, 0);
            // D: row p = kg*4+r, col c = nt*16+col; store pre-split bf16
            #pragma unroll
            for (int r = 0; r < 4; ++r) {
                int p = kg * 4 + r;
                if (p < PKP) {
                    unsigned short hu, lu;
                    split1(acc[r], hu, lu);
                    int off = pl * WROW + p * PSTR + nt * 16 + col;
                    wfsH[off] = hu;
                    wfsL[off] = lu;
                }
            }
        }
    }
    __syncthreads();

    // ---- phase 2: y = wf @ Wkp (K=960), wave w owns n-tile w ----
    f32x4 a0 = {0.f, 0.f, 0.f, 0.f};
    f32x4 a1 = {0.f, 0.f, 0.f, 0.f};
    f32x4 a2 = {0.f, 0.f, 0.f, 0.f};
    #pragma unroll
    for (int kt = 0; kt < 30; ++kt) {
        int koff = col * WROW + (kt >> 1) * PSTR + (kt & 1) * 32 + k8;
        v8bf ah = as_v8bf(*(const uint4*)&wfsH[koff]);
        v8bf al = as_v8bf(*(const uint4*)&wfsL[koff]);
        int bidx = ((kt << 2) + w) * 64 + l;
        v8bf bh = as_v8bf(WkpPh[bidx]);
        v8bf bl = as_v8bf(WkpPl[bidx]);
        a0 = __builtin_amdgcn_mfma_f32_16x16x32_bf16(ah, bh, a0, 0, 0, 0);
        a1 = __builtin_amdgcn_mfma_f32_16x16x32_bf16(al, bh, a1, 0, 0, 0);
        a2 = __builtin_amdgcn_mfma_f32_16x16x32_bf16(ah, bl, a2, 0, 0, 0);
    }
    // y D-frag: row = point = kg*4+r, col d = w*16+col; lrelu; split; store
    #pragma unroll
    for (int r = 0; r < 4; ++r) {
        float yv = lrelu(a0[r] + a1[r] + a2[r]);
        unsigned short hu, lu;
        split1(yv, hu, lu);
        int off = (kg * 4 + r) * YROW + w * 16 + col;
        yH[off] = hu;
        yL[off] = lu;
    }
    __syncthreads();

    // ---- phase 3: out = lrelu(lrelu(bn2(y @ W2)) + sc), K=64 ----
    f32x4 acc2[4];
    #pragma unroll
    for (int i = 0; i < 4; ++i) acc2[i] = (f32x4){0.f, 0.f, 0.f, 0.f};
    #pragma unroll
    for (int kt = 0; kt < 2; ++kt) {
        int yoff = col * YROW + kt * 32 + k8;
        v8bf ah = as_v8bf(*(const uint4*)&yH[yoff]);
        v8bf al = as_v8bf(*(const uint4*)&yL[yoff]);
        #pragma unroll
        for (int ntl = 0; ntl < 4; ++ntl) {
            int nt2 = w * 4 + ntl;
            int bidx = (((kt << 4) + nt2) << 6) + l;
            v8bf bh = as_v8bf(W2Ph[bidx]);
            v8bf bl = as_v8bf(W2Pl[bidx]);
            acc2[ntl] = __builtin_amdgcn_mfma_f32_16x16x32_bf16(ah, bh, acc2[ntl], 0, 0, 0);
            acc2[ntl] = __builtin_amdgcn_mfma_f32_16x16x32_bf16(al, bh, acc2[ntl], 0, 0, 0);
            acc2[ntl] = __builtin_amdgcn_mfma_f32_16x16x32_bf16(ah, bl, acc2[ntl], 0, 0, 0);
        }
    }
    #pragma unroll
    for (int ntl = 0; ntl < 4; ++ntl) {
        int cold = (w * 4 + ntl) * 16 + col;
        float sc = bnscale[320 + cold], sh = bnshift[320 + cold];
        #pragma unroll
        for (int r = 0; r < 4; ++r) {
            int n = n0 + kg * 4 + r;
            float val = lrelu(acc2[ntl][r] * sc + sh);
            float scv = scbuf[(size_t)n * COUT + cold];
            out[(size_t)n * COUT + cold] = lrelu(val + scv);
        }
    }
}

// ---------------------------------------------------------------------------
extern "C" void kernel_launch(void* const* d_in, const int* in_sizes, int n_in,
                              void* d_out, int out_size, void* d_ws, size_t ws_size,
                              hipStream_t stream)
{
    const float* F   = (const float*)d_in[0];
    const float* pts = (const float*)d_in[1];
    const int*   nid = (const int*)d_in[2];
    const float* W1  = (const float*)d_in[3];
    const float* g1  = (const float*)d_in[4];
    const float* b1  = (const float*)d_in[5];
    const float* m1  = (const float*)d_in[6];
    const float* v1  = (const float*)d_in[7];
    const float* kpp = (const float*)d_in[8];
    const float* Wkp = (const float*)d_in[9];
    const float* W2  = (const float*)d_in[10];
    const float* g2  = (const float*)d_in[11];
    const float* b2  = (const float*)d_in[12];
    const float* m2  = (const float*)d_in[13];
    const float* v2  = (const float*)d_in[14];
    const float* Ws  = (const float*)d_in[15];
    const float* gs  = (const float*)d_in[16];
    const float* bs  = (const float*)d_in[17];
    const float* ms  = (const float*)d_in[18];
    const float* vs  = (const float*)d_in[19];

    const int N = in_sizes[0] / CIN;   // 40000

    unsigned* xp   = (unsigned*)d_ws;                 // [N,64] packed bf16 pair
    float* scbuf   = (float*)(xp + (size_t)N * MID);  // [N,256] f32
    uint4* WkpPh   = (uint4*)(scbuf + (size_t)N * COUT);
    uint4* WkpPl   = WkpPh + 7680;
    uint4* WcPh    = WkpPl + 7680;
    uint4* WcPl    = WcPh + 5120;
    uint4* W2Ph    = WcPl + 5120;
    uint4* W2Pl    = W2Ph + 2048;
    float* bnscale = (float*)(W2Pl + 2048);           // 576
    float* bnshift = bnscale + 576;
    float* out     = (float*)d_out;

    prep<<<61, 256, 0, stream>>>(Wkp, W1, Ws, W2,
                                 g1, b1, m1, v1, gs, bs, ms, vs, g2, b2, m2, v2,
                                 WkpPh, WkpPl, WcPh, WcPl, W2Ph, W2Pl,
                                 bnscale, bnshift);
    k1_mfma<<<N / 64, 256, 0, stream>>>(F, WcPh, WcPl, bnscale, bnshift, xp, scbuf);
    k234_fused<<<N / 16, 256, 0, stream>>>(xp, pts, nid, kpp,
                                           WkpPh, WkpPl, W2Ph, W2Pl,
                                           bnscale, bnshift, scbuf, out);
}

// Round 7
// 220.907 us; speedup vs baseline: 1.6343x; 1.0728x over previous
//
#include <hip/hip_runtime.h>
#include <math.h>

#define EPSBN 1e-5f

constexpr int CIN  = 128;
constexpr int MID  = 64;
constexpr int COUT = 256;
constexpr int KNB  = 32;
constexpr int PKP  = 15;

constexpr int PSTR = 72;           // wfs p-slot stride (elements); 16B-aligned
constexpr int WROW = PKP * PSTR;   // 1080 elements per point-row
constexpr int YROW = 72;           // y row stride (elements)

typedef __bf16 v8bf  __attribute__((ext_vector_type(8)));
typedef float  f32x4 __attribute__((ext_vector_type(4)));

__device__ __forceinline__ float lrelu(float x) { return x >= 0.0f ? x : 0.1f * x; }

// ---- bf16 split helpers (native cvt; RNE; residual-compensated) ----
__device__ __forceinline__ void split1(float v, unsigned short& h, unsigned short& l) {
    __bf16 hb = (__bf16)v;
    float r = v - (float)hb;
    __bf16 lb = (__bf16)r;
    h = __builtin_bit_cast(unsigned short, hb);
    l = __builtin_bit_cast(unsigned short, lb);
}

__device__ __forceinline__ void split_frag8(const float* s, v8bf& hi, v8bf& lo) {
    #pragma unroll
    for (int j = 0; j < 8; ++j) {
        __bf16 hb = (__bf16)s[j];
        float r = s[j] - (float)hb;
        hi[j] = hb;
        lo[j] = (__bf16)r;
    }
}

__device__ __forceinline__ v8bf as_v8bf(uint4 u) {
    union { uint4 u; v8bf v; } X;
    X.u = u;
    return X.v;
}

// bit-trick split (used by prep only; proven)
__device__ __forceinline__ unsigned bf16_rne(float f) {
    unsigned u = __float_as_uint(f);
    return (u + 0x7fffu + ((u >> 16) & 1u)) >> 16;
}
__device__ __forceinline__ void split_pack8(const float* s, v8bf& hi, v8bf& lo) {
    unsigned h[8], l[8];
    #pragma unroll
    for (int j = 0; j < 8; ++j) {
        float a = s[j];
        unsigned hu = bf16_rne(a);
        float r = a - __uint_as_float(hu << 16);
        h[j] = hu;
        l[j] = bf16_rne(r);
    }
    union { uint4 u; v8bf v; } H, L;
    H.u = make_uint4(h[0] | (h[1] << 16), h[2] | (h[3] << 16),
                     h[4] | (h[5] << 16), h[6] | (h[7] << 16));
    L.u = make_uint4(l[0] | (l[1] << 16), l[2] | (l[3] << 16),
                     l[4] | (l[5] << 16), l[6] | (l[7] << 16));
    hi = H.v;
    lo = L.v;
}

// ---------------------------------------------------------------------------
// prep: pack weights into MFMA B-fragment order (hi/lo bf16), precompute BN.
// B-frag: lane l holds B[k = kt*32+(l>>4)*8+j][col = nt*16+(l&15)], one uint4.
//   Wkp: 30 kt x 4 nt -> 7680 uint4 each; Wc=[W1|Ws]: 4 kt x 20 nt -> 5120;
//   W2: 2 kt x 16 nt -> 2048; bnscale/bnshift[576]: bn1, bns, bn2.
// ---------------------------------------------------------------------------
__global__ __launch_bounds__(256) void prep(
    const float* __restrict__ Wkp, const float* __restrict__ W1,
    const float* __restrict__ Ws,  const float* __restrict__ W2,
    const float* __restrict__ g1, const float* __restrict__ b1,
    const float* __restrict__ m1, const float* __restrict__ v1,
    const float* __restrict__ gs, const float* __restrict__ bs,
    const float* __restrict__ ms, const float* __restrict__ vs,
    const float* __restrict__ g2, const float* __restrict__ b2,
    const float* __restrict__ m2, const float* __restrict__ v2,
    uint4* __restrict__ WkpPh, uint4* __restrict__ WkpPl,
    uint4* __restrict__ WcPh,  uint4* __restrict__ WcPl,
    uint4* __restrict__ W2Ph,  uint4* __restrict__ W2Pl,
    float* __restrict__ bnscale, float* __restrict__ bnshift)
{
    const int b = blockIdx.x, t = threadIdx.x;
    if (b < 30) {                       // Wkp pack
        int gt = b * 256 + t;
        int lane = gt & 63, rest = gt >> 6;
        int nt = rest & 3, kt = rest >> 2;
        int col = nt * 16 + (lane & 15);
        int kbase = kt * 32 + ((lane >> 4) << 3);
        float tmp[8];
        #pragma unroll
        for (int j = 0; j < 8; ++j)
            tmp[j] = Wkp[(size_t)(kbase + j) * MID + col];
        v8bf hi, lo;
        split_pack8(tmp, hi, lo);
        union { v8bf v; uint4 u; } H, L; H.v = hi; L.v = lo;
        WkpPh[gt] = H.u; WkpPl[gt] = L.u;
    } else if (b < 50) {                // Wc = [W1|Ws] pack
        int gt = (b - 30) * 256 + t;
        int lane = gt & 63, rest = gt >> 6;
        int kt = rest / 20, nt = rest % 20;
        int c = nt * 16 + (lane & 15);
        int kbase = kt * 32 + ((lane >> 4) << 3);
        float tmp[8];
        #pragma unroll
        for (int j = 0; j < 8; ++j) {
            int k = kbase + j;
            tmp[j] = (c < 64) ? W1[(size_t)k * MID + c]
                              : Ws[(size_t)k * COUT + (c - 64)];
        }
        v8bf hi, lo;
        split_pack8(tmp, hi, lo);
        union { v8bf v; uint4 u; } H, L; H.v = hi; L.v = lo;
        WcPh[gt] = H.u; WcPl[gt] = L.u;
    } else if (b < 58) {                // W2 pack
        int gt = (b - 50) * 256 + t;
        int lane = gt & 63, rest = gt >> 6;
        int kt = rest >> 4, nt = rest & 15;
        int col = nt * 16 + (lane & 15);
        int kbase = kt * 32 + ((lane >> 4) << 3);
        float tmp[8];
        #pragma unroll
        for (int j = 0; j < 8; ++j)
            tmp[j] = W2[(size_t)(kbase + j) * COUT + col];
        v8bf hi, lo;
        split_pack8(tmp, hi, lo);
        union { v8bf v; uint4 u; } H, L; H.v = hi; L.v = lo;
        W2Ph[gt] = H.u; W2Pl[gt] = L.u;
    } else {                            // BN constants, 576 values
        int v = (b - 58) * 256 + t;
        if (v < 576) {
            float g, bb, mm, vv;
            if (v < 64)       { g = g1[v]; bb = b1[v]; mm = m1[v]; vv = v1[v]; }
            else if (v < 320) { int c = v - 64;  g = gs[c]; bb = bs[c]; mm = ms[c]; vv = vs[c]; }
            else              { int c = v - 320; g = g2[c]; bb = b2[c]; mm = m2[c]; vv = v2[c]; }
            float s = g / sqrtf(vv + EPSBN);
            bnscale[v] = s;
            bnshift[v] = bb - mm * s;
        }
    }
}

// ---------------------------------------------------------------------------
// K1 (MFMA, no LDS): [64 x 128] @ [128 x 160] per block; grid (N/64, 2).
// A-fragments loaded DIRECTLY from F (no staging, no barrier): lane reads
// F[n0 + w*16 + (l&15)][kt*32 + (l>>4)*8 + j] — 16 rows x 128B fully-consumed
// segments per load, each F element read exactly once per wave.
// Cols 0..63 -> xp packed (hi<<16|lo); cols 64..319 -> scbuf f32.
// ---------------------------------------------------------------------------
__global__ __launch_bounds__(256) void k1_mfma(
    const float* __restrict__ F,
    const uint4* __restrict__ WcPh, const uint4* __restrict__ WcPl,
    const float* __restrict__ bnscale, const float* __restrict__ bnshift,
    unsigned* __restrict__ xp, float* __restrict__ scbuf)
{
    const int t = threadIdx.x;
    const int l = t & 63, w = t >> 6;
    const int n0 = blockIdx.x * 64;
    const int ntbase = blockIdx.y * 10;
    const int colr = l & 15, kg = l >> 4;
    const int arow = n0 + w * 16 + colr;
    const int k8 = kg * 8;

    // issue all 8 A loads up-front (4 kt x 2 float4)
    const float* fr = F + (size_t)arow * CIN + k8;
    float4 av[4][2];
    #pragma unroll
    for (int kt = 0; kt < 4; ++kt) {
        av[kt][0] = *(const float4*)(fr + kt * 32);
        av[kt][1] = *(const float4*)(fr + kt * 32 + 4);
    }

    f32x4 acc[10];
    #pragma unroll
    for (int nt = 0; nt < 10; ++nt) acc[nt] = (f32x4){0.f, 0.f, 0.f, 0.f};

    #pragma unroll
    for (int kt = 0; kt < 4; ++kt) {
        float tmp[8] = {av[kt][0].x, av[kt][0].y, av[kt][0].z, av[kt][0].w,
                        av[kt][1].x, av[kt][1].y, av[kt][1].z, av[kt][1].w};
        v8bf ah, al;
        split_frag8(tmp, ah, al);
        #pragma unroll
        for (int nt = 0; nt < 10; ++nt) {
            int bidx = ((kt * 20 + ntbase + nt) << 6) + l;
            v8bf bh = as_v8bf(WcPh[bidx]);
            v8bf bl = as_v8bf(WcPl[bidx]);
            acc[nt] = __builtin_amdgcn_mfma_f32_16x16x32_bf16(ah, bh, acc[nt], 0, 0, 0);
            acc[nt] = __builtin_amdgcn_mfma_f32_16x16x32_bf16(al, bh, acc[nt], 0, 0, 0);
            acc[nt] = __builtin_amdgcn_mfma_f32_16x16x32_bf16(ah, bl, acc[nt], 0, 0, 0);
        }
    }

    const int rq = kg * 4;
    #pragma unroll
    for (int nt = 0; nt < 10; ++nt) {
        int col = (ntbase + nt) * 16 + colr;
        float sc = bnscale[col], sh = bnshift[col];
        #pragma unroll
        for (int r = 0; r < 4; ++r) {
            int row = n0 + w * 16 + rq + r;
            float val = lrelu(acc[nt][r] * sc + sh);
            if (col < 64) {
                unsigned short hu, lu;
                split1(val, hu, lu);
                xp[(size_t)row * MID + col] = ((unsigned)hu << 16) | lu;
            } else {
                scbuf[(size_t)row * COUT + (col - 64)] = val;
            }
        }
    }
}

// ---------------------------------------------------------------------------
// K234 (fused KPConv-MFMA + y-GEMM + tail-GEMM): 512 threads = 8 waves,
// 16 points per block (2x occupancy vs 256-thread version: 16 waves/CU).
// Phase 1: wave w computes wf for points w*2, w*2+1 (same math as verified).
// Phase 2: split-K — wave w handles n-tile (w&3), K-half (w>>2) of 30 kt;
//   upper half writes f32 partials to yP; lower half adds, lrelu, splits
//   to yH/yL.
// Phase 3: wave w does 2 of 16 output col-tiles; fused bn2+lrelu+sc+lrelu.
// ---------------------------------------------------------------------------
__global__ __launch_bounds__(512) void k234_fused(
    const unsigned* __restrict__ xp,
    const float* __restrict__ pts,
    const int* __restrict__ nidx,
    const float* __restrict__ kpp,
    const uint4* __restrict__ WkpPh, const uint4* __restrict__ WkpPl,
    const uint4* __restrict__ W2Ph,  const uint4* __restrict__ W2Pl,
    const float* __restrict__ bnscale, const float* __restrict__ bnshift,
    const float* __restrict__ scbuf,
    float* __restrict__ out)
{
    __shared__ unsigned short wfsH[16 * WROW];   // 33.75 KB
    __shared__ unsigned short wfsL[16 * WROW];   // 33.75 KB
    __shared__ float         yP[4][16][17];      // 4.25 KB split-K partials
    __shared__ unsigned short yH[16 * YROW];     // 2.25 KB
    __shared__ unsigned short yL[16 * YROW];     // 2.25 KB

    const int t = threadIdx.x;
    const int l = t & 63, w = t >> 6;            // w in 0..7
    const int col = l & 15, kg = l >> 4;
    const int k8 = kg * 8;
    const int n0 = blockIdx.x * 16;

    // kernel point for this lane's A-row (p = col); p==15 -> h = 0
    float kx = 0.f, ky = 0.f, kz = 0.f;
    if (col < PKP) { kx = kpp[col * 3]; ky = kpp[col * 3 + 1]; kz = kpp[col * 3 + 2]; }

    // ---- phase 1: per-point KPConv via MFMA (2 points per wave) ----
    for (int pt = 0; pt < 2; ++pt) {
        const int pl = w * 2 + pt;
        const int n  = n0 + pl;
        const float cx = pts[(size_t)n * 3];
        const float cy = pts[(size_t)n * 3 + 1];
        const float cz = pts[(size_t)n * 3 + 2];
        const int4 nba = ((const int4*)nidx)[(size_t)n * 8 + kg * 2];
        const int4 nbb = ((const int4*)nidx)[(size_t)n * 8 + kg * 2 + 1];
        int nb[8] = {nba.x, nba.y, nba.z, nba.w, nbb.x, nbb.y, nbb.z, nbb.w};

        // gather packed features: u[j][nt] covers B[k=k8+j][c=nt*16+col]
        unsigned u[8][4];
        #pragma unroll
        for (int j = 0; j < 8; ++j) {
            const unsigned* xr = xp + (size_t)nb[j] * MID + col;
            u[j][0] = xr[0];
            u[j][1] = xr[16];
            u[j][2] = xr[32];
            u[j][3] = xr[48];
        }

        // influence h for (p=col, k=k8+j) -> A-fragment
        float hv[8];
        #pragma unroll
        for (int j = 0; j < 8; ++j) {
            float ex = (pts[(size_t)nb[j] * 3]     - cx) - kx;
            float ey = (pts[(size_t)nb[j] * 3 + 1] - cy) - ky;
            float ez = (pts[(size_t)nb[j] * 3 + 2] - cz) - kz;
            float dist = sqrtf(ex * ex + ey * ey + ez * ez);
            float h = fmaxf(0.0f, 1.0f - dist * 20.0f);   // 1/KP_EXTENT
            hv[j] = (col < PKP) ? h : 0.0f;
        }
        v8bf ah, al;
        split_frag8(hv, ah, al);

        #pragma unroll
        for (int nt = 0; nt < 4; ++nt) {
            unsigned bhW[4], blW[4];
            #pragma unroll
            for (int i = 0; i < 4; ++i) {
                unsigned u0 = u[2 * i][nt], u1 = u[2 * i + 1][nt];
                bhW[i] = (u1 & 0xFFFF0000u) | (u0 >> 16);
                blW[i] = (u1 << 16) | (u0 & 0xFFFFu);
            }
            v8bf bh = as_v8bf(make_uint4(bhW[0], bhW[1], bhW[2], bhW[3]));
            v8bf bl = as_v8bf(make_uint4(blW[0], blW[1], blW[2], blW[3]));
            f32x4 acc = {0.f, 0.f, 0.f, 0.f};
            acc = __builtin_amdgcn_mfma_f32_16x16x32_bf16(ah, bh, acc, 0, 0, 0);
            acc = __builtin_amdgcn_mfma_f32_16x16x32_bf16(al, bh, acc, 0, 0, 0);
            acc = __builtin_amdgcn_mfma_f32_16x16x32_bf16(ah, bl, acc, 0, 0, 0);
            // D: row p = kg*4+r, col c = nt*16+col; store pre-split bf16
            #pragma unroll
            for (int r = 0; r < 4; ++r) {
                int p = kg * 4 + r;
                if (p < PKP) {
                    unsigned short hu, lu;
                    split1(acc[r], hu, lu);
                    int off = pl * WROW + p * PSTR + nt * 16 + col;
                    wfsH[off] = hu;
                    wfsL[off] = lu;
                }
            }
        }
    }
    __syncthreads();

    // ---- phase 2: y = wf @ Wkp (K=960) split-K across wave pairs ----
    const int nt = w & 3;        // n-tile
    const int khalf = w >> 2;    // 0: kt 0..14, 1: kt 15..29
    f32x4 a0 = {0.f, 0.f, 0.f, 0.f};
    f32x4 a1 = {0.f, 0.f, 0.f, 0.f};
    f32x4 a2 = {0.f, 0.f, 0.f, 0.f};
    #pragma unroll
    for (int i = 0; i < 15; ++i) {
        int kt = khalf * 15 + i;
        int koff = col * WROW + (kt >> 1) * PSTR + (kt & 1) * 32 + k8;
        v8bf ah = as_v8bf(*(const uint4*)&wfsH[koff]);
        v8bf al = as_v8bf(*(const uint4*)&wfsL[koff]);
        int bidx = ((kt << 2) + nt) * 64 + l;
        v8bf bh = as_v8bf(WkpPh[bidx]);
        v8bf bl = as_v8bf(WkpPl[bidx]);
        a0 = __builtin_amdgcn_mfma_f32_16x16x32_bf16(ah, bh, a0, 0, 0, 0);
        a1 = __builtin_amdgcn_mfma_f32_16x16x32_bf16(al, bh, a1, 0, 0, 0);
        a2 = __builtin_amdgcn_mfma_f32_16x16x32_bf16(ah, bl, a2, 0, 0, 0);
    }
    if (khalf == 1) {
        #pragma unroll
        for (int r = 0; r < 4; ++r)
            yP[nt][kg * 4 + r][col] = a0[r] + a1[r] + a2[r];
    }
    __syncthreads();
    if (khalf == 0) {
        #pragma unroll
        for (int r = 0; r < 4; ++r) {
            float yv = lrelu(a0[r] + a1[r] + a2[r] + yP[nt][kg * 4 + r][col]);
            unsigned short hu, lu;
            split1(yv, hu, lu);
            int off = (kg * 4 + r) * YROW + nt * 16 + col;
            yH[off] = hu;
            yL[off] = lu;
        }
    }
    __syncthreads();

    // ---- phase 3: out = lrelu(lrelu(bn2(y @ W2)) + sc), 2 col-tiles/wave --
    f32x4 acc2[2];
    #pragma unroll
    for (int i = 0; i < 2; ++i) acc2[i] = (f32x4){0.f, 0.f, 0.f, 0.f};
    #pragma unroll
    for (int kt = 0; kt < 2; ++kt) {
        int yoff = col * YROW + kt * 32 + k8;
        v8bf ah = as_v8bf(*(const uint4*)&yH[yoff]);
        v8bf al = as_v8bf(*(const uint4*)&yL[yoff]);
        #pragma unroll
        for (int ii = 0; ii < 2; ++ii) {
            int nt2 = w * 2 + ii;
            int bidx = (((kt << 4) + nt2) << 6) + l;
            v8bf bh = as_v8bf(W2Ph[bidx]);
            v8bf bl = as_v8bf(W2Pl[bidx]);
            acc2[ii] = __builtin_amdgcn_mfma_f32_16x16x32_bf16(ah, bh, acc2[ii], 0, 0, 0);
            acc2[ii] = __builtin_amdgcn_mfma_f32_16x16x32_bf16(al, bh, acc2[ii], 0, 0, 0);
            acc2[ii] = __builtin_amdgcn_mfma_f32_16x16x32_bf16(ah, bl, acc2[ii], 0, 0, 0);
        }
    }
    #pragma unroll
    for (int ii = 0; ii < 2; ++ii) {
        int cold = (w * 2 + ii) * 16 + col;
        float sc = bnscale[320 + cold], sh = bnshift[320 + cold];
        #pragma unroll
        for (int r = 0; r < 4; ++r) {
            int n = n0 + kg * 4 + r;
            float val = lrelu(acc2[ii][r] * sc + sh);
            float scv = scbuf[(size_t)n * COUT + cold];
            out[(size_t)n * COUT + cold] = lrelu(val + scv);
        }
    }
}

// ---------------------------------------------------------------------------
extern "C" void kernel_launch(void* const* d_in, const int* in_sizes, int n_in,
                              void* d_out, int out_size, void* d_ws, size_t ws_size,
                              hipStream_t stream)
{
    const float* F   = (const float*)d_in[0];
    const float* pts = (const float*)d_in[1];
    const int*   nid = (const int*)d_in[2];
    const float* W1  = (const float*)d_in[3];
    const float* g1  = (const float*)d_in[4];
    const float* b1  = (const float*)d_in[5];
    const float* m1  = (const float*)d_in[6];
    const float* v1  = (const float*)d_in[7];
    const float* kpp = (const float*)d_in[8];
    const float* Wkp = (const float*)d_in[9];
    const float* W2  = (const float*)d_in[10];
    const float* g2  = (const float*)d_in[11];
    const float* b2  = (const float*)d_in[12];
    const float* m2  = (const float*)d_in[13];
    const float* v2  = (const float*)d_in[14];
    const float* Ws  = (const float*)d_in[15];
    const float* gs  = (const float*)d_in[16];
    const float* bs  = (const float*)d_in[17];
    const float* ms  = (const float*)d_in[18];
    const float* vs  = (const float*)d_in[19];

    const int N = in_sizes[0] / CIN;   // 40000

    unsigned* xp   = (unsigned*)d_ws;                 // [N,64] packed bf16 pair
    float* scbuf   = (float*)(xp + (size_t)N * MID);  // [N,256] f32
    uint4* WkpPh   = (uint4*)(scbuf + (size_t)N * COUT);
    uint4* WkpPl   = WkpPh + 7680;
    uint4* WcPh    = WkpPl + 7680;
    uint4* WcPl    = WcPh + 5120;
    uint4* W2Ph    = WcPl + 5120;
    uint4* W2Pl    = W2Ph + 2048;
    float* bnscale = (float*)(W2Pl + 2048);           // 576
    float* bnshift = bnscale + 576;
    float* out     = (float*)d_out;

    prep<<<61, 256, 0, stream>>>(Wkp, W1, Ws, W2,
                                 g1, b1, m1, v1, gs, bs, ms, vs, g2, b2, m2, v2,
                                 WkpPh, WkpPl, WcPh, WcPl, W2Ph, W2Pl,
                                 bnscale, bnshift);
    k1_mfma<<<dim3(N / 64, 2), 256, 0, stream>>>(F, WcPh, WcPl, bnscale, bnshift, xp, scbuf);
    k234_fused<<<N / 16, 512, 0, stream>>>(xp, pts, nid, kpp,
                                           WkpPh, WkpPl, W2Ph, W2Pl,
                                           bnscale, bnshift, scbuf, out);
}